// Round 13
// baseline (204.299 us; speedup 1.0000x reference)
//
#include <hip/hip_runtime.h>
#include <hip/hip_bf16.h>
#include <cstdint>

#define DEV __device__ __forceinline__

typedef short  s16x8 __attribute__((ext_vector_type(8)));
typedef short  s16x4 __attribute__((ext_vector_type(4)));
typedef unsigned short u16x8 __attribute__((ext_vector_type(8)));
typedef float  f32x4 __attribute__((ext_vector_type(4)));
typedef __hip_bfloat16 bf16;

DEV short f2bf(float f) {
    __hip_bfloat16 h = __float2bfloat16(f);
    return __builtin_bit_cast(short, h);
}

DEV f32x4 vmax4(f32x4 a, f32x4 b) {
    f32x4 r;
#pragma unroll
    for (int j = 0; j < 4; ++j) r[j] = fmaxf(a[j], b[j]);
    return r;
}

// global -> LDS async copy, 16B per lane; LDS base must be wave-uniform.
DEV void gload_lds16(const void* g, void* l) {
    __builtin_amdgcn_global_load_lds(
        (const __attribute__((address_space(1))) uint32_t*)g,
        (__attribute__((address_space(3))) uint32_t*)l, 16, 0, 0);
}

// ---------------------------------------------------------------- prep (one launch)
// z=0: attn_w^T (768x2304->T)  z=1: proj_w^T  z=2: sum_r text_w^T
// z=3: bias_text (x<3) + latf INIT (3<=x<9: bias+ones-row terms)  z=4: x fp32->bf16
__global__ void prep_all(const float* __restrict__ x, const float* __restrict__ aw,
                         const float* __restrict__ pw, const float* __restrict__ tw,
                         const float* __restrict__ tb, const float* __restrict__ lat,
                         const float* __restrict__ lw, const float* __restrict__ lb,
                         bf16* __restrict__ x_bf, bf16* __restrict__ awT,
                         bf16* __restrict__ pwT, bf16* __restrict__ twT,
                         float* __restrict__ tbias, float* __restrict__ latf) {
    const int z = blockIdx.z;
    if (z == 4) {  // convert x
        const int idx = blockIdx.y * 72 + blockIdx.x;
        if (idx >= 1536) return;
        const int i = (idx * 256 + threadIdx.x) * 8;
        f32x4 a = *(const f32x4*)&x[i];
        f32x4 c = *(const f32x4*)&x[i + 4];
        u16x8 o;
#pragma unroll
        for (int j = 0; j < 4; ++j) {
            o[j]     = (unsigned short)f2bf(a[j]);
            o[4 + j] = (unsigned short)f2bf(c[j]);
        }
        *(u16x8*)&x_bf[i] = o;
        return;
    }
    if (z == 3) {
        if (blockIdx.y != 0) return;
        const int xk = blockIdx.x;
        if (xk < 3) {  // bias_text
            const int o = xk * 256 + threadIdx.x;
            float s = 0.f;
#pragma unroll
            for (int r = 0; r < 4; ++r)
                s += tw[((size_t)r * 769 + 768) * 768 + o] + tb[r * 768 + o];
            tbias[o] = s;
        } else if (xk < 9) {  // latf init: ones-row of lat_w + summed bias
            const int idx = (xk - 3) * 256 + threadIdx.x;  // 0..1535
            const int bb = idx >= 768 ? 1 : 0;
            const int o = idx - bb * 768;
            float s = 0.f;
#pragma unroll
            for (int r = 0; r < 4; ++r)
                s += lw[((size_t)r * 769 + 768) * 768 + o] + lb[r * 768 + o];
            latf[bb * 768 + o] = s;
        }
        return;
    }
    // transposes
    __shared__ float t[32][33];
    const float* in; bf16* out; int C, G; size_t rstr;
    if (z == 0)      { in = aw; out = awT; C = 2304; G = 1; rstr = 0; }
    else if (z == 1) { in = pw; out = pwT; C = 768;  G = 1; rstr = 0; }
    else             { in = tw; out = twT; C = 768;  G = 4; rstr = 769ul * 768; }
    const int c0 = blockIdx.x * 32, r0 = blockIdx.y * 32;
    if (c0 >= C) return;
    const int tx = threadIdx.x & 31, ty = threadIdx.x >> 5;
#pragma unroll
    for (int i = 0; i < 32; i += 8) {
        float s = 0.f;
        for (int g = 0; g < G; ++g)
            s += in[g * rstr + (size_t)(r0 + ty + i) * C + c0 + tx];
        t[ty + i][tx] = s;
    }
    __syncthreads();
#pragma unroll
    for (int i = 0; i < 32; i += 8)
        out[(size_t)(c0 + ty + i) * 768 + r0 + tx] = __float2bfloat16(t[tx][ty + i]);
}

// latf accumulation: latf[b][o] += sum_{i<768} lat[b][i] * sum_r lat_w[r][i][o].
// grid (12 o-chunks of 64, 8 i-chunks of 96); o coalesced across lanes; lw read
// once per block, used for both b; LDS partial-reduce, 1 atomicAdd per (b,o).
__global__ __launch_bounds__(256) void latf_partial(
    const float* __restrict__ lat, const float* __restrict__ lw,
    float* __restrict__ latf) {
    const int oc = blockIdx.x, ic = blockIdx.y;
    const int ol = threadIdx.x & 63, wv = threadIdx.x >> 6;
    const int o = oc * 64 + ol;
    float s0 = 0.f, s1 = 0.f;
#pragma unroll 4
    for (int t = 0; t < 24; ++t) {
        const int i = ic * 96 + wv * 24 + t;
        float wsum = 0.f;
#pragma unroll
        for (int r = 0; r < 4; ++r) wsum += lw[((size_t)r * 769 + i) * 768 + o];
        s0 += lat[i] * wsum;
        s1 += lat[768 + i] * wsum;
    }
    __shared__ float ps[2][4][64];
    ps[0][wv][ol] = s0;
    ps[1][wv][ol] = s1;
    __syncthreads();
    if (threadIdx.x < 128) {
        const int bb = threadIdx.x >> 6;
        float v = ps[bb][0][ol] + ps[bb][1][ol] + ps[bb][2][ol] + ps[bb][3][ol];
        atomicAdd(&latf[bb * 768 + o], v);
    }
}

// ---------------------------------------------------------------- GEMM (m97 structure)
// C[M,N] = A[M,K] @ Bt[N,K]^T ; 128xTN tile, BK=32, 4 waves, 16x16x32 bf16 MFMA.
// EPI 0: +bias -> bf16 qkv for cols<1536; V-cols (>=1536) go ONLY to vT[bh][d][s].
// EPI 1: (acc+bias)*latf*(0.125*log2e) -> bf16 (fused q)   EPI 2: +bias -> f32
template <int EPI, int TN>
__global__ __launch_bounds__(256) void gemm_bt(
    const bf16* __restrict__ A, int lda, const bf16* __restrict__ Bt,
    const float* __restrict__ bias, const float* __restrict__ latf,
    void* __restrict__ Cout, bf16* __restrict__ vTout, int ldc, int K) {
    constexpr int FN = TN / 32;
    __shared__ bf16 Al[128 * 32];
    __shared__ bf16 Bl[TN * 32];
    const int tid = threadIdx.x, w = tid >> 6, lane = tid & 63;
    const int row0 = blockIdx.x * 128, col0 = blockIdx.y * TN;
    const int wm = (w >> 1) * 64, wn = (w & 1) * (TN / 2);
    const int lr = lane & 15, lk8 = (lane >> 4) * 8, lq = lane >> 4;
    const int sr = lane >> 2;
    const int sc = (lane & 3) * 8;
    f32x4 acc[4][FN] = {};
    for (int k0 = 0; k0 < K; k0 += 32) {
#pragma unroll
        for (int i = 0; i < 2; ++i) {
            const int rr = w * 32 + i * 16;
            gload_lds16(A + (size_t)(row0 + rr + sr) * lda + k0 + sc, &Al[rr * 32]);
        }
#pragma unroll
        for (int i = 0; i < TN / 64; ++i) {
            const int rb = (w * (TN / 64) + i) * 16;
            gload_lds16(Bt + (size_t)(col0 + rb + sr) * K + k0 + sc, &Bl[rb * 32]);
        }
        __syncthreads();
        s16x8 af[4], bfr[FN];
#pragma unroll
        for (int m = 0; m < 4; ++m) af[m]  = *(const s16x8*)&Al[(wm + m * 16 + lr) * 32 + lk8];
#pragma unroll
        for (int n = 0; n < FN; ++n) bfr[n] = *(const s16x8*)&Bl[(wn + n * 16 + lr) * 32 + lk8];
        __builtin_amdgcn_s_setprio(1);
#pragma unroll
        for (int m = 0; m < 4; ++m)
#pragma unroll
            for (int n = 0; n < FN; ++n)
                acc[m][n] = __builtin_amdgcn_mfma_f32_16x16x32_bf16(af[m], bfr[n], acc[m][n], 0, 0, 0);
        __builtin_amdgcn_s_setprio(0);
        __syncthreads();
    }
#pragma unroll
    for (int m = 0; m < 4; ++m)
#pragma unroll
        for (int n = 0; n < FN; ++n) {
            const int rowb = row0 + wm + m * 16 + lq * 4;  // r spans rowb..rowb+3
            const int col  = col0 + wn + n * 16 + lr;
            if (EPI == 0 && col0 >= 1536) {
                // V region: write only vT[bh][d][s] (packed over r = consecutive s)
                const int vcol = col - 1536;
                s16x4 vo;
#pragma unroll
                for (int r = 0; r < 4; ++r) vo[r] = f2bf(acc[m][n][r] + bias[col]);
                bf16* vdst = vTout +
                    ((size_t)((rowb >> 11) * 12 + (vcol >> 6)) * 64 + (vcol & 63)) * 2048 +
                    (rowb & 2047);
                *(s16x4*)vdst = vo;
            } else {
#pragma unroll
                for (int r = 0; r < 4; ++r) {
                    const int row = rowb + r;
                    const float v = acc[m][n][r];
                    if (EPI == 0) {
                        ((bf16*)Cout)[(size_t)row * ldc + col] = __float2bfloat16(v + bias[col]);
                    } else if (EPI == 1) {
                        ((bf16*)Cout)[(size_t)row * ldc + col] = __float2bfloat16(
                            (v + bias[col]) * latf[(row >> 11) * 768 + col] * 0.18033688011112042f);
                    } else {
                        ((float*)Cout)[(size_t)row * ldc + col] = v + bias[col];
                    }
                }
            }
        }
}

// ---------------------------------------------------------------- flash attention
// 768 blocks x 4 waves (256 thr): block = one 64-row q-tile of one (b,h).
// bh = blk%24 (24%8==0 => all blocks of a head on the SAME XCD); p = 31-blk/24.
// T4 counted-vmcnt pipeline (replaces __syncthreads): per iter,
//   STAGE(t+1) -> s_waitcnt vmcnt(4) (tile t's 4 loads done; t+1's stay in
//   flight) -> s_barrier -> compute buf[cur] -> lgkmcnt(0) -> s_barrier.
// Prefetch gets a FULL iteration of slack instead of draining at each barrier.
// K (64x64) and V^T (64x64) LDS-staged double-buffered via global_load_lds,
// XOR-swizzled (linear LDS dest + pre-swizzled global src + swizzled ds_read).
// Swapped QK^T: lane owns q-row (lr); softmax = in-lane max + 2 shfl; P via
// per-wave LDS; PV: O^T = mfma(V^T, P^T). exp2 domain (log2e*0.125 in qf).
__global__ __launch_bounds__(256, 3) void attn_k(
    const bf16* __restrict__ qf, const bf16* __restrict__ qkv,
    const bf16* __restrict__ vT, bf16* __restrict__ aout) {
    __shared__ bf16 KL[2][4096];
    __shared__ bf16 VL[2][4096];
    __shared__ unsigned short Pl[4][16][68];
    const int w = threadIdx.x >> 6, lane = threadIdx.x & 63;
    const int bh = blockIdx.x % 24;          // same XCD for all blocks of a head
    const int p  = 31 - blockIdx.x / 24;     // heavy tiles dispatch first
    const int b = bh / 12, h = bh - b * 12;
    const int lr = lane & 15, lq = lane >> 4;
    // staging: 256 threads cover 32 rows x 8 chunks per issue; 2 issues per tile.
    // row r slot c holds global chunk c^(r&7) (XOR swizzle, linear LDS dest).
    const int st_row = threadIdx.x >> 3;                    // 0..31
    const int st_ck  = (threadIdx.x & 7) ^ (st_row & 7);    // pre-swizzled source
    const bf16* Kg = qkv + (size_t)b * 2048 * 2304 + 768 + h * 64;  // rows = keys
    const bf16* Vg = vT + (size_t)bh * 64 * 2048;                   // rows = d

    auto STAGE = [&](int t, int buf) {
        const int kv0s = t * 64;
#pragma unroll
        for (int half = 0; half < 2; ++half) {
            const int r0 = half * 32;  // wave-uniform LDS chunk: rows r0+8w..r0+8w+7
            gload_lds16(Kg + (size_t)(kv0s + r0 + st_row) * 2304 + st_ck * 8,
                        &KL[buf][(r0 + 8 * w) * 64]);
            gload_lds16(Vg + (size_t)(r0 + st_row) * 2048 + kv0s + st_ck * 8,
                        &VL[buf][(r0 + 8 * w) * 64]);
        }
    };

    const int qw = 64 * p + 16 * w;          // wave's first q-row (seq pos)
    const size_t grow = (size_t)b * 2048 + qw;
    s16x8 qa0, qa1;
    {
        const bf16* qp = qf + (grow + lr) * 768 + h * 64 + lq * 8;
        qa0 = *(const s16x8*)qp;
        qa1 = *(const s16x8*)(qp + 32);
    }
    float mr = -3.0e38f, lsum = 0.f;
    f32x4 oacc[4] = {};
    const int T = p + 1;
    int myT = (qw + 79) >> 6;
    if (myT > T) myT = T;
    STAGE(0, 0);
    for (int t = 0; t < T; ++t) {
        const int cur = t & 1;
        // barrier A: tile t's loads complete everywhere; t+1's stay in flight.
        if (t + 1 < T) {
            STAGE(t + 1, cur ^ 1);
            asm volatile("s_waitcnt vmcnt(4)" ::: "memory");
        } else {
            asm volatile("s_waitcnt vmcnt(0)" ::: "memory");
        }
        __builtin_amdgcn_s_barrier();
        __builtin_amdgcn_sched_barrier(0);
        if (t < myT) {
            const int kv0 = t * 64;
            f32x4 st[4] = {};
            __builtin_amdgcn_s_setprio(1);
#pragma unroll
            for (int ks = 0; ks < 2; ++ks) {
                const int ck = ((4 * ks + lq) ^ (lr & 7)) * 8;
                const s16x8 qa = ks ? qa1 : qa0;
#pragma unroll
                for (int n = 0; n < 4; ++n) {
                    s16x8 kb = *(const s16x8*)&KL[cur][(n * 16 + lr) * 64 + ck];
                    st[n] = __builtin_amdgcn_mfma_f32_16x16x32_bf16(kb, qa, st[n], 0, 0, 0);
                }
            }
            __builtin_amdgcn_s_setprio(0);
            if (kv0 + 63 > qw) {  // diagonal tile(s): causal mask
#pragma unroll
                for (int n = 0; n < 4; ++n)
#pragma unroll
                    for (int r = 0; r < 4; ++r)
                        if (kv0 + n * 16 + lq * 4 + r > qw + lr) st[n][r] = -10000.f;
            }
            // online softmax (exp2 domain); lane owns row q=lr
            f32x4 m4 = vmax4(vmax4(st[0], st[1]), vmax4(st[2], st[3]));
            float v = fmaxf(fmaxf(m4[0], m4[1]), fmaxf(m4[2], m4[3]));
            v = fmaxf(v, __shfl_xor(v, 16));
            v = fmaxf(v, __shfl_xor(v, 32));
            const float newm = fmaxf(mr, v);
            const float scl = __builtin_amdgcn_exp2f(mr - newm);
            mr = newm;
#pragma unroll
            for (int n = 0; n < 4; ++n)
#pragma unroll
                for (int e = 0; e < 4; ++e)
                    st[n][e] = __builtin_amdgcn_exp2f(st[n][e] - newm);
            f32x4 ps4 = (st[0] + st[1]) + (st[2] + st[3]);
            lsum = lsum * scl + ((ps4[0] + ps4[1]) + (ps4[2] + ps4[3]));
#pragma unroll
            for (int dn = 0; dn < 4; ++dn) oacc[dn] *= scl;
            // P -> per-wave LDS (transpose to B-fragment layout)
#pragma unroll
            for (int n = 0; n < 4; ++n) {
                s16x4 pk;
#pragma unroll
                for (int r = 0; r < 4; ++r) pk[r] = f2bf(st[n][r]);
                *(s16x4*)&Pl[w][lr][n * 16 + lq * 4] = pk;
            }
            __builtin_amdgcn_s_setprio(1);
#pragma unroll
            for (int ks = 0; ks < 2; ++ks) {
                const s16x8 pb = *(const s16x8*)&Pl[w][lr][ks * 32 + lq * 8];
                const int ck = ((4 * ks + lq) ^ (lr & 7)) * 8;
#pragma unroll
                for (int dn = 0; dn < 4; ++dn) {
                    s16x8 vb = *(const s16x8*)&VL[cur][(dn * 16 + lr) * 64 + ck];
                    oacc[dn] = __builtin_amdgcn_mfma_f32_16x16x32_bf16(vb, pb, oacc[dn], 0, 0, 0);
                }
            }
            __builtin_amdgcn_s_setprio(0);
        }
        // barrier B: all reads of buf[cur] retired before next STAGE overwrites it.
        __builtin_amdgcn_sched_barrier(0);
        asm volatile("s_waitcnt lgkmcnt(0)" ::: "memory");
        __builtin_amdgcn_s_barrier();
    }
    lsum += __shfl_xor(lsum, 16);
    lsum += __shfl_xor(lsum, 32);
    const float inv = 1.0f / lsum;
#pragma unroll
    for (int dn = 0; dn < 4; ++dn) {
        s16x4 o4;
#pragma unroll
        for (int r = 0; r < 4; ++r) o4[r] = f2bf(oacc[dn][r] * inv);
        *(s16x4*)&aout[(grow + lr) * 768 + h * 64 + dn * 16 + lq * 4] = o4;
    }
}

// ---------------------------------------------------------------- launch

extern "C" void kernel_launch(void* const* d_in, const int* in_sizes, int n_in,
                              void* d_out, int out_size, void* d_ws, size_t ws_size,
                              hipStream_t stream) {
    (void)in_sizes; (void)n_in; (void)out_size; (void)ws_size;
    const float* x      = (const float*)d_in[0];
    const float* lat    = (const float*)d_in[1];
    const float* attn_w = (const float*)d_in[2];
    const float* attn_b = (const float*)d_in[3];
    const float* proj_w = (const float*)d_in[4];
    const float* proj_b = (const float*)d_in[5];
    const float* text_w = (const float*)d_in[6];
    const float* text_b = (const float*)d_in[7];
    const float* lat_w  = (const float*)d_in[8];
    const float* lat_b  = (const float*)d_in[9];
    float* out = (float*)d_out;

    char* ws = (char*)d_ws;
    size_t off = 0;
    auto take = [&](size_t bytes) -> char* {
        char* p = ws + off;
        off = (off + bytes + 255) & ~(size_t)255;
        return p;
    };
    bf16* x_bf   = (bf16*)take(4096ul * 768 * 2);
    bf16* awT    = (bf16*)take(2304ul * 768 * 2);
    bf16* pwT    = (bf16*)take(768ul * 768 * 2);
    bf16* twT    = (bf16*)take(768ul * 768 * 2);
    bf16* qkv_bf = (bf16*)take(4096ul * 2304 * 2);
    bf16* qf_bf  = (bf16*)take(4096ul * 768 * 2);
    bf16* vT     = (bf16*)take(24ul * 64 * 2048 * 2);
    bf16* a_bf   = (bf16*)take(4096ul * 768 * 2);
    float* tbias = (float*)take(768 * 4);
    float* latf  = (float*)take(2 * 768 * 4);

    prep_all<<<dim3(72, 24, 5), 256, 0, stream>>>(x, attn_w, proj_w, text_w, text_b,
                                                  lat, lat_w, lat_b, x_bf, awT, pwT,
                                                  twT, tbias, latf);
    latf_partial<<<dim3(12, 8), 256, 0, stream>>>(lat, lat_w, latf);
    gemm_bt<0, 128><<<dim3(32, 18), 256, 0, stream>>>(x_bf, 768, awT, attn_b, nullptr,
                                                      qkv_bf, vT, 2304, 768);
    gemm_bt<1, 64><<<dim3(32, 12), 256, 0, stream>>>(qkv_bf, 2304, twT, tbias, latf,
                                                     qf_bf, nullptr, 768, 768);
    attn_k<<<768, 256, 0, stream>>>(qf_bf, qkv_bf, vT, a_bf);
    gemm_bt<2, 64><<<dim3(32, 12), 256, 0, stream>>>(a_bf, 768, pwT, proj_b, nullptr,
                                                     out, nullptr, 768, 768);
}